// Round 3
// baseline (425.025 us; speedup 1.0000x reference)
//
#include <hip/hip_runtime.h>
#include <math.h>

#define B_ 8
#define N_ 1024
#define D_ 512
#define H_ 4
#define ND (N_ * D_)      // 524288
#define DD (D_ * D_)      // 262144
#define NN (N_ * N_)      // 1048576

typedef _Float16 f16;
typedef f16 f16x8 __attribute__((ext_vector_type(8)));
typedef f16 f16x4 __attribute__((ext_vector_type(4)));
typedef float f32x4 __attribute__((ext_vector_type(4)));

typedef __attribute__((address_space(3))) void lds_void;
typedef __attribute__((address_space(1))) void g_void;

// =====================================================================
// Uniform m97-structure GEMM: C[128][128] tile, BK=32, 16x16x32 f16 MFMA,
// 2 LDS buffers (16 KB), global_load_lds width-16 staging.
// K axis is segmented in 512-wide chunks; each segment selects its own
// A/B base pointer (wave-uniform scalar select). This folds hi/lo
// split-precision products into ONE plain GEMM loop.
// EPI 0: store f16 hi/lo pair.  EPI 1: store fp32 * scale.
// =====================================================================
template<int NSEG, int EPI, int LDA, int LDB, int LDC, int KTOT>
__device__ __forceinline__ void gemm_core(
    const f16* __restrict__ A0, const f16* __restrict__ A1, const f16* __restrict__ A2,
    const f16* __restrict__ B0, const f16* __restrict__ B1, const f16* __restrict__ B2,
    float* __restrict__ Cf, f16* __restrict__ Ch, f16* __restrict__ Cl, float scale)
{
    __shared__ f16 sA[128 * 32];
    __shared__ f16 sB[128 * 32];

    const int n0 = blockIdx.y * 128;   // output row tile
    const int c0 = blockIdx.x * 128;   // output col tile

    const int t = threadIdx.x;
    const int w = t >> 6;              // wave 0..3
    const int l = t & 63;              // lane
    const int lrow = l >> 2;           // staging sub-row 0..15
    const int lch  = l & 3;            // staging 16B chunk 0..3
    const int wr = w >> 1, wc = w & 1; // wave's 64x64 quadrant
    const int fr = l & 15;             // fragment row/col
    const int fq = l >> 4;             // fragment quad 0..3

    f32x4 acc[4][4] = {};

    for (int k0 = 0; k0 < KTOT; k0 += 32) {
        const int seg = k0 >> 9;       // 512-wide segments
        const int ko  = k0 & 511;
        const f16* Ab = (seg == 0) ? A0 : ((seg == 1) ? A1 : A2);
        const f16* Bb = (seg == 0) ? B0 : ((seg == 1) ? B1 : B2);

        // ---- stage A,B : global -> LDS, 16B/lane ----
#pragma unroll
        for (int i = 0; i < 2; ++i) {
            const int rb  = w * 2 + i;            // row-block 0..7
            const int row = rb * 16 + lrow;       // 0..127
            const f16* ga = Ab + (size_t)(n0 + row) * LDA + ko + lch * 8;
            __builtin_amdgcn_global_load_lds((g_void*)ga, (lds_void*)(sA + rb * 512), 16, 0, 0);
            const f16* gb = Bb + (size_t)(c0 + row) * LDB + ko + lch * 8;
            __builtin_amdgcn_global_load_lds((g_void*)gb, (lds_void*)(sB + rb * 512), 16, 0, 0);
        }
        __syncthreads();

        // ---- fragments ----
        f16x8 af[4], bf[4];
#pragma unroll
        for (int i = 0; i < 4; ++i) {
            af[i] = *(const f16x8*)(sA + (wr * 64 + i * 16 + fr) * 32 + fq * 8);
            bf[i] = *(const f16x8*)(sB + (wc * 64 + i * 16 + fr) * 32 + fq * 8);
        }

        // ---- MFMA ----
#pragma unroll
        for (int i = 0; i < 4; ++i)
#pragma unroll
            for (int j = 0; j < 4; ++j)
                acc[i][j] = __builtin_amdgcn_mfma_f32_16x16x32_f16(af[i], bf[j], acc[i][j], 0, 0, 0);
        __syncthreads();
    }

    // ---- epilogue: C/D layout col=lane&15, row=quad*4+reg ----
#pragma unroll
    for (int i = 0; i < 4; ++i)
#pragma unroll
        for (int j = 0; j < 4; ++j)
#pragma unroll
            for (int r = 0; r < 4; ++r) {
                const int row = n0 + wr * 64 + i * 16 + fq * 4 + r;
                const int col = c0 + wc * 64 + j * 16 + fr;
                const size_t idx = (size_t)row * LDC + col;
                if constexpr (EPI == 1) {
                    Cf[idx] = acc[i][j][r] * scale;
                } else {
                    const float v = acc[i][j][r];
                    const f16 hh = (f16)v;
                    Ch[idx] = hh;
                    Cl[idx] = (f16)(v - (float)hh);
                }
            }
}

// GEMM1: Y[z] = x[b] @ W[h], fp16 2-product (x single, W hi/lo). K'=1024.
__global__ __launch_bounds__(256) void k_g1(
    const f16* __restrict__ xfh, const f16* __restrict__ wTh,
    const f16* __restrict__ wTl, f16* __restrict__ Yh, f16* __restrict__ Yl,
    int zbase)
{
    const int z = blockIdx.z, zg = zbase + z;
    const int b = zg >> 2, h = zg & 3;
    const f16* A = xfh + (size_t)b * ND;
    gemm_core<2, 0, D_, D_, D_, 1024>(
        A, A, nullptr,
        wTh + (size_t)h * DD, wTl + (size_t)h * DD, nullptr,
        nullptr, Yh + (size_t)z * ND, Yl + (size_t)z * ND, 1.0f);
}

// GEMM2: S[z] = Y[z] @ x[b]^T * scale, fp16 3-product. K'=1536.
// products: Yh*xh + Yl*xh + Yh*xl
__global__ __launch_bounds__(256) void k_g2(
    const f16* __restrict__ Yh, const f16* __restrict__ Yl,
    const f16* __restrict__ xfh, const f16* __restrict__ xfl,
    float* __restrict__ S, int zbase)
{
    const int z = blockIdx.z, zg = zbase + z;
    const int b = zg >> 2;
    const f16* Ah = Yh + (size_t)z * ND;
    const f16* Al = Yl + (size_t)z * ND;
    const f16* Bh = xfh + (size_t)b * ND;
    const f16* Bl = xfl + (size_t)b * ND;
    gemm_core<3, 1, D_, D_, N_, 1536>(
        Ah, Al, Ah, Bh, Bh, Bl,
        S + (size_t)z * NN, nullptr, nullptr, 0.044194173824159216f);
}

// GEMM4 split-K by head: part[b*4+h] = P[b,h] @ xT[b]^T, K=1024 (2 segs).
__global__ __launch_bounds__(256) void k_g4(
    const f16* __restrict__ P, const f16* __restrict__ xT,
    float* __restrict__ part)
{
    const int z = blockIdx.z;             // z = b*4+h, 0..31
    const int b = z >> 2;
    const f16* A = P + (size_t)z * NN;    // rows n, k=m, stride 1024
    const f16* Bt = xT + (size_t)b * ND;  // rows d, k=m, stride 1024
    gemm_core<2, 1, N_, N_, D_, 1024>(
        A, A + 512, nullptr, Bt, Bt + 512, nullptr,
        part + (size_t)z * ND, nullptr, nullptr, 1.0f);
}

// Reduce: out[b] = 0.25 * sum_h part[b*4+h]
__global__ __launch_bounds__(256) void k_reduce(
    const float* __restrict__ part, float* __restrict__ out)
{
    const int i = blockIdx.x * 256 + threadIdx.x;   // float4 index
    const int b = i / (ND / 4);
    const int r = i - b * (ND / 4);
    const float4* p = (const float4*)part;
    float4 a0 = p[(size_t)(b * 4 + 0) * (ND / 4) + r];
    float4 a1 = p[(size_t)(b * 4 + 1) * (ND / 4) + r];
    float4 a2 = p[(size_t)(b * 4 + 2) * (ND / 4) + r];
    float4 a3 = p[(size_t)(b * 4 + 3) * (ND / 4) + r];
    float4 o;
    o.x = 0.25f * (a0.x + a1.x + a2.x + a3.x);
    o.y = 0.25f * (a0.y + a1.y + a2.y + a3.y);
    o.z = 0.25f * (a0.z + a1.z + a2.z + a3.z);
    o.w = 0.25f * (a0.w + a1.w + a2.w + a3.w);
    ((float4*)out)[i] = o;
}

// Decompose x -> fp16 hi/lo and transposed hi [b][d][n]
__global__ __launch_bounds__(256) void decomp_x(
    const float* __restrict__ x, f16* __restrict__ xfh,
    f16* __restrict__ xfl, f16* __restrict__ xT)
{
    __shared__ f16 tile[64][65];
    const int b = blockIdx.z, n0 = blockIdx.y * 64, d0 = blockIdx.x * 64;
    const float* xb = x + (size_t)b * ND;
    const int t = threadIdx.x;
#pragma unroll
    for (int p = 0; p < 16; ++p) {
        const int idx = t + p * 256;
        const int r = idx >> 6, c = idx & 63;
        const float v = xb[(size_t)(n0 + r) * D_ + d0 + c];
        const f16 h = (f16)v;
        const size_t o = (size_t)b * ND + (size_t)(n0 + r) * D_ + d0 + c;
        xfh[o] = h;
        xfl[o] = (f16)(v - (float)h);
        tile[r][c] = h;
    }
    __syncthreads();
#pragma unroll
    for (int p = 0; p < 16; ++p) {
        const int idx = t + p * 256;
        const int r = idx >> 6, c = idx & 63;   // r = local d, c = local n
        xT[(size_t)b * ND + (size_t)(d0 + r) * N_ + n0 + c] = tile[c][r];
    }
}

// Decompose + transpose W: W[h][d][e] -> wTh/wTl fp16 [h][e][d]
__global__ __launch_bounds__(256) void decomp_w(
    const float* __restrict__ W, f16* __restrict__ wTh, f16* __restrict__ wTl)
{
    __shared__ float tw[64][65];
    const int h = blockIdx.z, d0 = blockIdx.y * 64, e0 = blockIdx.x * 64;
    const float* Wh = W + (size_t)h * DD;
    const int t = threadIdx.x;
#pragma unroll
    for (int p = 0; p < 16; ++p) {
        const int idx = t + p * 256;
        const int r = idx >> 6, c = idx & 63;
        tw[r][c] = Wh[(size_t)(d0 + r) * D_ + e0 + c];
    }
    __syncthreads();
#pragma unroll
    for (int p = 0; p < 16; ++p) {
        const int idx = t + p * 256;
        const int r = idx >> 6, c = idx & 63;   // r = local e, c = local d
        const float v = tw[c][r];
        const f16 hh = (f16)v;
        const size_t o = (size_t)h * DD + (size_t)(e0 + r) * D_ + d0 + c;
        wTh[o] = hh;
        wTl[o] = (f16)(v - (float)hh);
    }
}

// Rowwise softmax fp32 S -> fp16 P. One block per row of 1024.
__global__ __launch_bounds__(256) void softmax_rows_f16(
    const float* __restrict__ S, f16* __restrict__ P)
{
    const size_t row = blockIdx.x;
    const float4* p = (const float4*)(S + row * (size_t)N_);
    const int t = threadIdx.x;

    float4 v = p[t];
    float m = fmaxf(fmaxf(v.x, v.y), fmaxf(v.z, v.w));
#pragma unroll
    for (int o = 32; o > 0; o >>= 1) m = fmaxf(m, __shfl_xor(m, o));

    __shared__ float wred[4];
    const int wave = t >> 6, lane = t & 63;
    if (lane == 0) wred[wave] = m;
    __syncthreads();
    m = fmaxf(fmaxf(wred[0], wred[1]), fmaxf(wred[2], wred[3]));

    v.x = __expf(v.x - m);
    v.y = __expf(v.y - m);
    v.z = __expf(v.z - m);
    v.w = __expf(v.w - m);
    float s = v.x + v.y + v.z + v.w;
#pragma unroll
    for (int o = 32; o > 0; o >>= 1) s += __shfl_xor(s, o);
    __syncthreads();
    if (lane == 0) wred[wave] = s;
    __syncthreads();
    s = wred[0] + wred[1] + wred[2] + wred[3];

    const float inv = 1.0f / s;
    f16x4 o4;
    o4[0] = (f16)(v.x * inv);
    o4[1] = (f16)(v.y * inv);
    o4[2] = (f16)(v.z * inv);
    o4[3] = (f16)(v.w * inv);
    *(f16x4*)(P + row * (size_t)N_ + t * 4) = o4;
}

extern "C" void kernel_launch(void* const* d_in, const int* in_sizes, int n_in,
                              void* d_out, int out_size, void* d_ws, size_t ws_size,
                              hipStream_t stream) {
    const float* x = (const float*)d_in[0];   // [8,1024,512]
    const float* W = (const float*)d_in[1];   // [4,512,512]
    float* out = (float*)d_out;               // [8,1024,512]

    // workspace layout, 188 MiB (same footprint R2 proved available)
    char* ws = (char*)d_ws;
    const size_t MB = 1024 * 1024;
    f16*   xfh = (f16*)(ws + 0 * MB);     // 8 MiB
    f16*   xfl = (f16*)(ws + 8 * MB);     // 8 MiB
    f16*   xT  = (f16*)(ws + 16 * MB);    // 8 MiB
    f16*   wTh = (f16*)(ws + 24 * MB);    // 2 MiB
    f16*   wTl = (f16*)(ws + 26 * MB);    // 2 MiB
    f16*   Yh  = (f16*)(ws + 28 * MB);    // 16 MiB (per-half, 16 z)
    f16*   Yl  = (f16*)(ws + 44 * MB);    // 16 MiB
    float* S   = (float*)(ws + 60 * MB);  // 64 MiB (per-half fp32)
    f16*   P   = (f16*)(ws + 124 * MB);   // 64 MiB (all 32 z, fp16)
    float* part = S;                      // gemm4 partials reuse S (dead then)

    decomp_x<<<dim3(D_ / 64, N_ / 64, B_), 256, 0, stream>>>(x, xfh, xfl, xT);
    decomp_w<<<dim3(D_ / 64, D_ / 64, H_), 256, 0, stream>>>(W, wTh, wTl);

    for (int half = 0; half < 2; ++half) {
        const int zbase = half * 16;
        k_g1<<<dim3(D_ / 128, N_ / 128, 16), 256, 0, stream>>>(
            xfh, wTh, wTl, Yh, Yl, zbase);
        k_g2<<<dim3(N_ / 128, N_ / 128, 16), 256, 0, stream>>>(
            Yh, Yl, xfh, xfl, S, zbase);
        softmax_rows_f16<<<dim3(16 * N_), 256, 0, stream>>>(
            S, P + (size_t)zbase * NN);
    }
    k_g4<<<dim3(D_ / 128, N_ / 128, 32), 256, 0, stream>>>(P, xT, part);
    k_reduce<<<dim3((B_ * ND / 4) / 256), 256, 0, stream>>>(part, out);
}

// Round 4
// 314.015 us; speedup vs baseline: 1.3535x; 1.3535x over previous
//
#include <hip/hip_runtime.h>
#include <math.h>

#define B_ 8
#define N_ 1024
#define D_ 512
#define H_ 4
#define ND (N_ * D_)      // 524288
#define DD (D_ * D_)      // 262144
#define NN (N_ * N_)      // 1048576

typedef _Float16 f16;
typedef f16 f16x8 __attribute__((ext_vector_type(8)));
typedef f16 f16x4 __attribute__((ext_vector_type(4)));
typedef float f32x4 __attribute__((ext_vector_type(4)));

typedef __attribute__((address_space(3))) void lds_void;
typedef __attribute__((address_space(1))) void g_void;

// =====================================================================
// m97-structure GEMM, 128x128 C-tile, BK=32, 16x16x32 f16 MFMA,
// global_load_lds width-16 staging, 2-barrier K-loop.
// NPROD=2: B comes as (B0,B1) pair; each staged ONCE per iter, A-fragments
// reused across both products (C = A*(B0+B1)^T). 32 MFMA / 3 staged tiles.
// EPI 0: store f16 (hi only).  EPI 1: store fp32 * scale.
// =====================================================================
template<int NPROD, int EPI, int LDA, int LDB, int LDC, int KTOT>
__device__ __forceinline__ void gemm_core(
    const f16* __restrict__ A, const f16* __restrict__ B0,
    const f16* __restrict__ B1,
    float* __restrict__ Cf, f16* __restrict__ Ch, float scale)
{
    __shared__ f16 sA[128 * 32];
    __shared__ f16 sB0[128 * 32];
    __shared__ f16 sB1[(NPROD == 2) ? 128 * 32 : 64];

    const int n0 = blockIdx.y * 128;   // output row tile
    const int c0 = blockIdx.x * 128;   // output col tile

    const int t = threadIdx.x;
    const int w = t >> 6;              // wave 0..3
    const int l = t & 63;              // lane
    const int lrow = l >> 2;           // staging sub-row 0..15
    const int lch  = l & 3;            // staging 16B chunk 0..3
    const int wr = w >> 1, wc = w & 1; // wave's 64x64 quadrant
    const int fr = l & 15;             // fragment row/col
    const int fq = l >> 4;             // fragment quad 0..3

    f32x4 acc[4][4] = {};

    for (int k0 = 0; k0 < KTOT; k0 += 32) {
        // ---- stage: global -> LDS, 16B/lane, each buffer once ----
#pragma unroll
        for (int i = 0; i < 2; ++i) {
            const int rb  = w * 2 + i;            // row-block 0..7
            const int row = rb * 16 + lrow;       // 0..127
            const f16* ga = A + (size_t)(n0 + row) * LDA + k0 + lch * 8;
            __builtin_amdgcn_global_load_lds((g_void*)ga, (lds_void*)(sA + rb * 512), 16, 0, 0);
            const f16* gb0 = B0 + (size_t)(c0 + row) * LDB + k0 + lch * 8;
            __builtin_amdgcn_global_load_lds((g_void*)gb0, (lds_void*)(sB0 + rb * 512), 16, 0, 0);
            if constexpr (NPROD == 2) {
                const f16* gb1 = B1 + (size_t)(c0 + row) * LDB + k0 + lch * 8;
                __builtin_amdgcn_global_load_lds((g_void*)gb1, (lds_void*)(sB1 + rb * 512), 16, 0, 0);
            }
        }
        __syncthreads();

        // ---- fragments (A reused across both products) ----
        f16x8 a[4], b0[4], b1[4];
#pragma unroll
        for (int i = 0; i < 4; ++i) {
            a[i]  = *(const f16x8*)(sA  + (wr * 64 + i * 16 + fr) * 32 + fq * 8);
            b0[i] = *(const f16x8*)(sB0 + (wc * 64 + i * 16 + fr) * 32 + fq * 8);
            if constexpr (NPROD == 2)
                b1[i] = *(const f16x8*)(sB1 + (wc * 64 + i * 16 + fr) * 32 + fq * 8);
        }

        // ---- MFMA: acc += a*b0 (+ a*b1) ----
#pragma unroll
        for (int i = 0; i < 4; ++i)
#pragma unroll
            for (int j = 0; j < 4; ++j) {
                acc[i][j] = __builtin_amdgcn_mfma_f32_16x16x32_f16(a[i], b0[j], acc[i][j], 0, 0, 0);
                if constexpr (NPROD == 2)
                    acc[i][j] = __builtin_amdgcn_mfma_f32_16x16x32_f16(a[i], b1[j], acc[i][j], 0, 0, 0);
            }
        __syncthreads();
    }

    // ---- epilogue: C/D layout col=lane&15, row=quad*4+reg ----
#pragma unroll
    for (int i = 0; i < 4; ++i)
#pragma unroll
        for (int j = 0; j < 4; ++j)
#pragma unroll
            for (int r = 0; r < 4; ++r) {
                const int row = n0 + wr * 64 + i * 16 + fq * 4 + r;
                const int col = c0 + wc * 64 + j * 16 + fr;
                const size_t idx = (size_t)row * LDC + col;
                if constexpr (EPI == 1)
                    Cf[idx] = acc[i][j][r] * scale;
                else
                    Ch[idx] = (f16)acc[i][j][r];
            }
}

// GEMM1 (full batch): Yh[z] = f16( x[b] @ (Wh+Wl)[h] ), z=b*4+h
__global__ __launch_bounds__(256) void k_g1(
    const f16* __restrict__ xfh, const f16* __restrict__ wTh,
    const f16* __restrict__ wTl, f16* __restrict__ Yh)
{
    const int z = blockIdx.z;
    const int b = z >> 2, h = z & 3;
    gemm_core<2, 0, D_, D_, D_, D_>(
        xfh + (size_t)b * ND,
        wTh + (size_t)h * DD, wTl + (size_t)h * DD,
        nullptr, Yh + (size_t)z * ND, 1.0f);
}

// GEMM2 (per half): S[z] = Yh[zg] @ (xh+xl)[b]^T * scale
__global__ __launch_bounds__(256) void k_g2(
    const f16* __restrict__ Yh, const f16* __restrict__ xfh,
    const f16* __restrict__ xfl, float* __restrict__ S, int zbase)
{
    const int z = blockIdx.z, zg = zbase + z;
    const int b = zg >> 2;
    gemm_core<2, 1, D_, D_, N_, D_>(
        Yh + (size_t)zg * ND,
        xfh + (size_t)b * ND, xfl + (size_t)b * ND,
        S + (size_t)z * NN, nullptr, 0.044194173824159216f);
}

// GEMM4 split-K by head: part[z] = P[z] @ xT[b]^T, K=1024, z=b*4+h
__global__ __launch_bounds__(256) void k_g4(
    const f16* __restrict__ P, const f16* __restrict__ xT,
    float* __restrict__ part)
{
    const int z = blockIdx.z;
    const int b = z >> 2;
    gemm_core<1, 1, N_, N_, D_, N_>(
        P + (size_t)z * NN,
        xT + (size_t)b * ND, nullptr,
        part + (size_t)z * ND, nullptr, 1.0f);
}

// Reduce: out[b] = 0.25 * sum_h part[b*4+h]
__global__ __launch_bounds__(256) void k_reduce(
    const float* __restrict__ part, float* __restrict__ out)
{
    const int i = blockIdx.x * 256 + threadIdx.x;   // float4 index
    const int b = i / (ND / 4);
    const int r = i - b * (ND / 4);
    const float4* p = (const float4*)part;
    float4 a0 = p[(size_t)(b * 4 + 0) * (ND / 4) + r];
    float4 a1 = p[(size_t)(b * 4 + 1) * (ND / 4) + r];
    float4 a2 = p[(size_t)(b * 4 + 2) * (ND / 4) + r];
    float4 a3 = p[(size_t)(b * 4 + 3) * (ND / 4) + r];
    float4 o;
    o.x = 0.25f * (a0.x + a1.x + a2.x + a3.x);
    o.y = 0.25f * (a0.y + a1.y + a2.y + a3.y);
    o.z = 0.25f * (a0.z + a1.z + a2.z + a3.z);
    o.w = 0.25f * (a0.w + a1.w + a2.w + a3.w);
    ((float4*)out)[i] = o;
}

// Decompose x -> fp16 hi/lo and transposed hi [b][d][n]
__global__ __launch_bounds__(256) void decomp_x(
    const float* __restrict__ x, f16* __restrict__ xfh,
    f16* __restrict__ xfl, f16* __restrict__ xT)
{
    __shared__ f16 tile[64][65];
    const int b = blockIdx.z, n0 = blockIdx.y * 64, d0 = blockIdx.x * 64;
    const float* xb = x + (size_t)b * ND;
    const int t = threadIdx.x;
#pragma unroll
    for (int p = 0; p < 16; ++p) {
        const int idx = t + p * 256;
        const int r = idx >> 6, c = idx & 63;
        const float v = xb[(size_t)(n0 + r) * D_ + d0 + c];
        const f16 h = (f16)v;
        const size_t o = (size_t)b * ND + (size_t)(n0 + r) * D_ + d0 + c;
        xfh[o] = h;
        xfl[o] = (f16)(v - (float)h);
        tile[r][c] = h;
    }
    __syncthreads();
#pragma unroll
    for (int p = 0; p < 16; ++p) {
        const int idx = t + p * 256;
        const int r = idx >> 6, c = idx & 63;   // r = local d, c = local n
        xT[(size_t)b * ND + (size_t)(d0 + r) * N_ + n0 + c] = tile[c][r];
    }
}

// Decompose + transpose W: W[h][d][e] -> wTh/wTl fp16 [h][e][d]
__global__ __launch_bounds__(256) void decomp_w(
    const float* __restrict__ W, f16* __restrict__ wTh, f16* __restrict__ wTl)
{
    __shared__ float tw[64][65];
    const int h = blockIdx.z, d0 = blockIdx.y * 64, e0 = blockIdx.x * 64;
    const float* Wh = W + (size_t)h * DD;
    const int t = threadIdx.x;
#pragma unroll
    for (int p = 0; p < 16; ++p) {
        const int idx = t + p * 256;
        const int r = idx >> 6, c = idx & 63;
        tw[r][c] = Wh[(size_t)(d0 + r) * D_ + e0 + c];
    }
    __syncthreads();
#pragma unroll
    for (int p = 0; p < 16; ++p) {
        const int idx = t + p * 256;
        const int r = idx >> 6, c = idx & 63;   // r = local e, c = local d
        const float v = tw[c][r];
        const f16 hh = (f16)v;
        const size_t o = (size_t)h * DD + (size_t)(e0 + r) * D_ + d0 + c;
        wTh[o] = hh;
        wTl[o] = (f16)(v - (float)hh);
    }
}

// Rowwise softmax fp32 S -> fp16 P. One block per row of 1024.
__global__ __launch_bounds__(256) void softmax_rows_f16(
    const float* __restrict__ S, f16* __restrict__ P)
{
    const size_t row = blockIdx.x;
    const float4* p = (const float4*)(S + row * (size_t)N_);
    const int t = threadIdx.x;

    float4 v = p[t];
    float m = fmaxf(fmaxf(v.x, v.y), fmaxf(v.z, v.w));
#pragma unroll
    for (int o = 32; o > 0; o >>= 1) m = fmaxf(m, __shfl_xor(m, o));

    __shared__ float wred[4];
    const int wave = t >> 6, lane = t & 63;
    if (lane == 0) wred[wave] = m;
    __syncthreads();
    m = fmaxf(fmaxf(wred[0], wred[1]), fmaxf(wred[2], wred[3]));

    v.x = __expf(v.x - m);
    v.y = __expf(v.y - m);
    v.z = __expf(v.z - m);
    v.w = __expf(v.w - m);
    float s = v.x + v.y + v.z + v.w;
#pragma unroll
    for (int o = 32; o > 0; o >>= 1) s += __shfl_xor(s, o);
    __syncthreads();
    if (lane == 0) wred[wave] = s;
    __syncthreads();
    s = wred[0] + wred[1] + wred[2] + wred[3];

    const float inv = 1.0f / s;
    f16x4 o4;
    o4[0] = (f16)(v.x * inv);
    o4[1] = (f16)(v.y * inv);
    o4[2] = (f16)(v.z * inv);
    o4[3] = (f16)(v.w * inv);
    *(f16x4*)(P + row * (size_t)N_ + t * 4) = o4;
}

extern "C" void kernel_launch(void* const* d_in, const int* in_sizes, int n_in,
                              void* d_out, int out_size, void* d_ws, size_t ws_size,
                              hipStream_t stream) {
    const float* x = (const float*)d_in[0];   // [8,1024,512]
    const float* W = (const float*)d_in[1];   // [4,512,512]
    float* out = (float*)d_out;               // [8,1024,512]

    // workspace layout, 188 MiB (footprint proven in R2/R3)
    char* ws = (char*)d_ws;
    const size_t MB = 1024 * 1024;
    f16*   xfh = (f16*)(ws + 0 * MB);     // 8 MiB
    f16*   xfl = (f16*)(ws + 8 * MB);     // 8 MiB
    f16*   xT  = (f16*)(ws + 16 * MB);    // 8 MiB
    f16*   wTh = (f16*)(ws + 24 * MB);    // 2 MiB
    f16*   wTl = (f16*)(ws + 26 * MB);    // 2 MiB
    f16*   Yh  = (f16*)(ws + 28 * MB);    // 32 MiB (full batch, 32 z)
    float* S   = (float*)(ws + 60 * MB);  // 64 MiB (per half fp32, 16 z)
    f16*   P   = (f16*)(ws + 124 * MB);   // 64 MiB (full, f16)
    float* part = S;                      // g4 partials reuse S (dead then)

    decomp_x<<<dim3(D_ / 64, N_ / 64, B_), 256, 0, stream>>>(x, xfh, xfl, xT);
    decomp_w<<<dim3(D_ / 64, D_ / 64, H_), 256, 0, stream>>>(W, wTh, wTl);

    // g1 full batch: 1024 blocks
    k_g1<<<dim3(D_ / 128, N_ / 128, B_ * H_), 256, 0, stream>>>(
        xfh, wTh, wTl, Yh);

    for (int half = 0; half < 2; ++half) {
        const int zbase = half * 16;
        k_g2<<<dim3(N_ / 128, N_ / 128, 16), 256, 0, stream>>>(
            Yh, xfh, xfl, S, zbase);
        softmax_rows_f16<<<dim3(16 * N_), 256, 0, stream>>>(
            S, P + (size_t)zbase * NN);
    }

    k_g4<<<dim3(D_ / 128, N_ / 128, B_ * H_), 256, 0, stream>>>(P, xT, part);
    k_reduce<<<dim3((B_ * ND / 4) / 256), 256, 0, stream>>>(part, out);
}

// Round 5
// 290.156 us; speedup vs baseline: 1.4648x; 1.0822x over previous
//
#include <hip/hip_runtime.h>
#include <math.h>

#define B_ 8
#define N_ 1024
#define D_ 512
#define H_ 4
#define ND (N_ * D_)      // 524288
#define DD (D_ * D_)      // 262144
#define NN (N_ * N_)      // 1048576

typedef _Float16 f16;
typedef f16 f16x8 __attribute__((ext_vector_type(8)));
typedef f16 f16x4 __attribute__((ext_vector_type(4)));
typedef float f32x4 __attribute__((ext_vector_type(4)));

typedef __attribute__((address_space(3))) void lds_void;
typedef __attribute__((address_space(1))) void g_void;

// =====================================================================
// m97-structure GEMM core, 128x128 C-tile, BK=32, 16x16x32 f16 MFMA,
// global_load_lds width-16 staging, 2-barrier K-loop.
// NPROD=2: B = (B0,B1), each staged once/iter, A-fragments reused:
// C = A*(B0+B1)^T, 32 MFMA / 3 staged tiles.
// EPI 0: store f16. EPI 1: store fp32*scale. EPI 2: store f16*scale.
// Block tile coords (n0,c0) are passed in (callers do XCD-affine swizzle).
// =====================================================================
template<int NPROD, int EPI, int LDA, int LDB, int LDC, int KTOT>
__device__ __forceinline__ void gemm_core(
    const f16* __restrict__ A, const f16* __restrict__ B0,
    const f16* __restrict__ B1,
    float* __restrict__ Cf, f16* __restrict__ Ch, float scale,
    int n0, int c0)
{
    __shared__ f16 sA[128 * 32];
    __shared__ f16 sB0[128 * 32];
    __shared__ f16 sB1[(NPROD == 2) ? 128 * 32 : 64];

    const int t = threadIdx.x;
    const int w = t >> 6;              // wave 0..3
    const int l = t & 63;              // lane
    const int lrow = l >> 2;           // staging sub-row 0..15
    const int lch  = l & 3;            // staging 16B chunk 0..3
    const int wr = w >> 1, wc = w & 1; // wave's 64x64 quadrant
    const int fr = l & 15;             // fragment row/col
    const int fq = l >> 4;             // fragment quad 0..3

    f32x4 acc[4][4] = {};

    for (int k0 = 0; k0 < KTOT; k0 += 32) {
        // ---- stage: global -> LDS, 16B/lane, each buffer once ----
#pragma unroll
        for (int i = 0; i < 2; ++i) {
            const int rb  = w * 2 + i;            // row-block 0..7
            const int row = rb * 16 + lrow;       // 0..127
            const f16* ga = A + (size_t)(n0 + row) * LDA + k0 + lch * 8;
            __builtin_amdgcn_global_load_lds((g_void*)ga, (lds_void*)(sA + rb * 512), 16, 0, 0);
            const f16* gb0 = B0 + (size_t)(c0 + row) * LDB + k0 + lch * 8;
            __builtin_amdgcn_global_load_lds((g_void*)gb0, (lds_void*)(sB0 + rb * 512), 16, 0, 0);
            if constexpr (NPROD == 2) {
                const f16* gb1 = B1 + (size_t)(c0 + row) * LDB + k0 + lch * 8;
                __builtin_amdgcn_global_load_lds((g_void*)gb1, (lds_void*)(sB1 + rb * 512), 16, 0, 0);
            }
        }
        __syncthreads();

        // ---- fragments (A reused across both products) ----
        f16x8 a[4], b0[4], b1[4];
#pragma unroll
        for (int i = 0; i < 4; ++i) {
            a[i]  = *(const f16x8*)(sA  + (wr * 64 + i * 16 + fr) * 32 + fq * 8);
            b0[i] = *(const f16x8*)(sB0 + (wc * 64 + i * 16 + fr) * 32 + fq * 8);
            if constexpr (NPROD == 2)
                b1[i] = *(const f16x8*)(sB1 + (wc * 64 + i * 16 + fr) * 32 + fq * 8);
        }

        // ---- MFMA ----
#pragma unroll
        for (int i = 0; i < 4; ++i)
#pragma unroll
            for (int j = 0; j < 4; ++j) {
                acc[i][j] = __builtin_amdgcn_mfma_f32_16x16x32_f16(a[i], b0[j], acc[i][j], 0, 0, 0);
                if constexpr (NPROD == 2)
                    acc[i][j] = __builtin_amdgcn_mfma_f32_16x16x32_f16(a[i], b1[j], acc[i][j], 0, 0, 0);
            }
        __syncthreads();
    }

    // ---- epilogue: C/D layout col=lane&15, row=quad*4+reg ----
#pragma unroll
    for (int i = 0; i < 4; ++i)
#pragma unroll
        for (int j = 0; j < 4; ++j)
#pragma unroll
            for (int r = 0; r < 4; ++r) {
                const int row = n0 + wr * 64 + i * 16 + fq * 4 + r;
                const int col = c0 + wc * 64 + j * 16 + fr;
                const size_t idx = (size_t)row * LDC + col;
                if constexpr (EPI == 1)
                    Cf[idx] = acc[i][j][r] * scale;
                else if constexpr (EPI == 2)
                    Ch[idx] = (f16)(acc[i][j][r] * scale);
                else
                    Ch[idx] = (f16)acc[i][j][r];
            }
}

// GEMM1: Yh[z] = f16( x[b] @ (Wh+Wl)[h] ), z=b*4+h.
// Swizzle: xcd = i&7 = b; li = i>>3: h = li>>5, n = (li>>2)&7, e = li&3.
__global__ __launch_bounds__(256) void k_g1(
    const f16* __restrict__ xfh, const f16* __restrict__ wTh,
    const f16* __restrict__ wTl, f16* __restrict__ Yh)
{
    const int i = blockIdx.x;
    const int b = i & 7;
    const int li = i >> 3;
    const int h = li >> 5;
    const int n0 = ((li >> 2) & 7) * 128;
    const int e0 = (li & 3) * 128;
    const int z = b * 4 + h;
    gemm_core<2, 0, D_, D_, D_, D_>(
        xfh + (size_t)b * ND,
        wTh + (size_t)h * DD, wTl + (size_t)h * DD,
        nullptr, Yh + (size_t)z * ND, 1.0f, n0, e0);
}

// GEMM2 (per half): S[z] = Yh[zg] @ (xh+xl)[b]^T * scale.
// Swizzle: xcd = i&7: b_local = xcd>>1, m-half = xcd&1;
// li = i>>3: h = li>>5, n = (li>>2)&7, mh = li&3.
__global__ __launch_bounds__(256) void k_g2(
    const f16* __restrict__ Yh, const f16* __restrict__ xfh,
    const f16* __restrict__ xfl, float* __restrict__ S, int zbase)
{
    const int i = blockIdx.x;
    const int xcd = i & 7;
    const int bl = xcd >> 1, sub = xcd & 1;
    const int li = i >> 3;
    const int h = li >> 5;
    const int n0 = ((li >> 2) & 7) * 128;
    const int m0 = (sub * 4 + (li & 3)) * 128;
    const int z = bl * 4 + h;            // local S index 0..15
    const int zg = zbase + z;
    const int b = (zbase >> 2) + bl;     // global batch
    gemm_core<2, 1, D_, D_, N_, D_>(
        Yh + (size_t)zg * ND,
        xfh + (size_t)b * ND, xfl + (size_t)b * ND,
        S + (size_t)z * NN, nullptr, 0.044194173824159216f, n0, m0);
}

// GEMM4 split-K by head: part[z] = f16( P[z] @ xT[b]^T ), z=b*4+h.
// Swizzle: xcd = i&7 = b; li = i>>3: h = li>>5, n = (li>>2)&7, d = li&3.
__global__ __launch_bounds__(256) void k_g4(
    const f16* __restrict__ P, const f16* __restrict__ xT,
    f16* __restrict__ part)
{
    const int i = blockIdx.x;
    const int b = i & 7;
    const int li = i >> 3;
    const int h = li >> 5;
    const int n0 = ((li >> 2) & 7) * 128;
    const int d0 = (li & 3) * 128;
    const int z = b * 4 + h;
    gemm_core<1, 2, N_, N_, D_, N_>(
        P + (size_t)z * NN,
        xT + (size_t)b * ND, nullptr,
        nullptr, part + (size_t)z * ND, 1.0f, n0, d0);
}

// Reduce: out[b] = 0.25 * sum_h part[b*4+h]   (f16 partials, 8 elems/thread)
__global__ __launch_bounds__(256) void k_reduce(
    const f16* __restrict__ part, float* __restrict__ out)
{
    const int i = blockIdx.x * 256 + threadIdx.x;   // 8-elem group index
    const int b = i / (ND / 8);
    const int r = i - b * (ND / 8);
    const f16x8* p = (const f16x8*)part;
    f16x8 a0 = p[(size_t)(b * 4 + 0) * (ND / 8) + r];
    f16x8 a1 = p[(size_t)(b * 4 + 1) * (ND / 8) + r];
    f16x8 a2 = p[(size_t)(b * 4 + 2) * (ND / 8) + r];
    f16x8 a3 = p[(size_t)(b * 4 + 3) * (ND / 8) + r];
    float4 o0, o1;
    float* o = (float*)&o0;
#pragma unroll
    for (int k = 0; k < 4; ++k)
        o[k] = 0.25f * ((float)a0[k] + (float)a1[k] + (float)a2[k] + (float)a3[k]);
    o = (float*)&o1;
#pragma unroll
    for (int k = 0; k < 4; ++k)
        o[k] = 0.25f * ((float)a0[k+4] + (float)a1[k+4] + (float)a2[k+4] + (float)a3[k+4]);
    ((float4*)out)[(size_t)i * 2]     = o0;
    ((float4*)out)[(size_t)i * 2 + 1] = o1;
}

// Decompose x -> fp16 hi/lo and transposed hi [b][d][n]
__global__ __launch_bounds__(256) void decomp_x(
    const float* __restrict__ x, f16* __restrict__ xfh,
    f16* __restrict__ xfl, f16* __restrict__ xT)
{
    __shared__ f16 tile[64][65];
    const int b = blockIdx.z, n0 = blockIdx.y * 64, d0 = blockIdx.x * 64;
    const float* xb = x + (size_t)b * ND;
    const int t = threadIdx.x;
#pragma unroll
    for (int p = 0; p < 16; ++p) {
        const int idx = t + p * 256;
        const int r = idx >> 6, c = idx & 63;
        const float v = xb[(size_t)(n0 + r) * D_ + d0 + c];
        const f16 h = (f16)v;
        const size_t o = (size_t)b * ND + (size_t)(n0 + r) * D_ + d0 + c;
        xfh[o] = h;
        xfl[o] = (f16)(v - (float)h);
        tile[r][c] = h;
    }
    __syncthreads();
#pragma unroll
    for (int p = 0; p < 16; ++p) {
        const int idx = t + p * 256;
        const int r = idx >> 6, c = idx & 63;   // r = local d, c = local n
        xT[(size_t)b * ND + (size_t)(d0 + r) * N_ + n0 + c] = tile[c][r];
    }
}

// Decompose + transpose W: W[h][d][e] -> wTh/wTl fp16 [h][e][d]
__global__ __launch_bounds__(256) void decomp_w(
    const float* __restrict__ W, f16* __restrict__ wTh, f16* __restrict__ wTl)
{
    __shared__ float tw[64][65];
    const int h = blockIdx.z, d0 = blockIdx.y * 64, e0 = blockIdx.x * 64;
    const float* Wh = W + (size_t)h * DD;
    const int t = threadIdx.x;
#pragma unroll
    for (int p = 0; p < 16; ++p) {
        const int idx = t + p * 256;
        const int r = idx >> 6, c = idx & 63;
        tw[r][c] = Wh[(size_t)(d0 + r) * D_ + e0 + c];
    }
    __syncthreads();
#pragma unroll
    for (int p = 0; p < 16; ++p) {
        const int idx = t + p * 256;
        const int r = idx >> 6, c = idx & 63;   // r = local e, c = local d
        const float v = tw[c][r];
        const f16 hh = (f16)v;
        const size_t o = (size_t)h * DD + (size_t)(e0 + r) * D_ + d0 + c;
        wTh[o] = hh;
        wTl[o] = (f16)(v - (float)hh);
    }
}

// Rowwise softmax fp32 S -> fp16 P. One block per row of 1024.
__global__ __launch_bounds__(256) void softmax_rows_f16(
    const float* __restrict__ S, f16* __restrict__ P)
{
    const size_t row = blockIdx.x;
    const float4* p = (const float4*)(S + row * (size_t)N_);
    const int t = threadIdx.x;

    float4 v = p[t];
    float m = fmaxf(fmaxf(v.x, v.y), fmaxf(v.z, v.w));
#pragma unroll
    for (int o = 32; o > 0; o >>= 1) m = fmaxf(m, __shfl_xor(m, o));

    __shared__ float wred[4];
    const int wave = t >> 6, lane = t & 63;
    if (lane == 0) wred[wave] = m;
    __syncthreads();
    m = fmaxf(fmaxf(wred[0], wred[1]), fmaxf(wred[2], wred[3]));

    v.x = __expf(v.x - m);
    v.y = __expf(v.y - m);
    v.z = __expf(v.z - m);
    v.w = __expf(v.w - m);
    float s = v.x + v.y + v.z + v.w;
#pragma unroll
    for (int o = 32; o > 0; o >>= 1) s += __shfl_xor(s, o);
    __syncthreads();
    if (lane == 0) wred[wave] = s;
    __syncthreads();
    s = wred[0] + wred[1] + wred[2] + wred[3];

    const float inv = 1.0f / s;
    f16x4 o4;
    o4[0] = (f16)(v.x * inv);
    o4[1] = (f16)(v.y * inv);
    o4[2] = (f16)(v.z * inv);
    o4[3] = (f16)(v.w * inv);
    *(f16x4*)(P + row * (size_t)N_ + t * 4) = o4;
}

extern "C" void kernel_launch(void* const* d_in, const int* in_sizes, int n_in,
                              void* d_out, int out_size, void* d_ws, size_t ws_size,
                              hipStream_t stream) {
    const float* x = (const float*)d_in[0];   // [8,1024,512]
    const float* W = (const float*)d_in[1];   // [4,512,512]
    float* out = (float*)d_out;               // [8,1024,512]

    // workspace layout, 188 MiB (footprint proven in R2-R4)
    char* ws = (char*)d_ws;
    const size_t MB = 1024 * 1024;
    f16*   xfh = (f16*)(ws + 0 * MB);     // 8 MiB
    f16*   xfl = (f16*)(ws + 8 * MB);     // 8 MiB
    f16*   xT  = (f16*)(ws + 16 * MB);    // 8 MiB
    f16*   wTh = (f16*)(ws + 24 * MB);    // 2 MiB
    f16*   wTl = (f16*)(ws + 26 * MB);    // 2 MiB
    f16*   Yh  = (f16*)(ws + 28 * MB);    // 32 MiB (full batch, 32 z)
    float* S   = (float*)(ws + 60 * MB);  // 64 MiB (per half fp32, 16 z)
    f16*   P   = (f16*)(ws + 124 * MB);   // 64 MiB (full, f16)
    f16*   part = (f16*)S;                // g4 partials (32 MiB) reuse S

    decomp_x<<<dim3(D_ / 64, N_ / 64, B_), 256, 0, stream>>>(x, xfh, xfl, xT);
    decomp_w<<<dim3(D_ / 64, D_ / 64, H_), 256, 0, stream>>>(W, wTh, wTl);

    k_g1<<<dim3(1024), 256, 0, stream>>>(xfh, wTh, wTl, Yh);

    for (int half = 0; half < 2; ++half) {
        const int zbase = half * 16;
        k_g2<<<dim3(1024), 256, 0, stream>>>(Yh, xfh, xfl, S, zbase);
        softmax_rows_f16<<<dim3(16 * N_), 256, 0, stream>>>(
            S, P + (size_t)zbase * NN);
    }

    k_g4<<<dim3(1024), 256, 0, stream>>>(P, xT, part);
    k_reduce<<<dim3((B_ * ND / 8) / 256), 256, 0, stream>>>(part, out);
}

// Round 6
// 255.081 us; speedup vs baseline: 1.6662x; 1.1375x over previous
//
#include <hip/hip_runtime.h>
#include <math.h>

#define B_ 8
#define N_ 1024
#define D_ 512
#define H_ 4
#define ND (N_ * D_)      // 524288
#define DD (D_ * D_)      // 262144
#define NN (N_ * N_)      // 1048576

typedef _Float16 f16;
typedef f16 f16x8 __attribute__((ext_vector_type(8)));
typedef f16 f16x4 __attribute__((ext_vector_type(4)));
typedef float f32x4 __attribute__((ext_vector_type(4)));

typedef __attribute__((address_space(3))) void lds_void;
typedef __attribute__((address_space(1))) void g_void;

// =====================================================================
// m97-structure GEMM core, 128x128 C-tile, 16x16x32 f16 MFMA,
// global_load_lds width-16 staging, 2-barrier K-loop.
// KSTEP = 32 or 64 (64 halves barrier count; LDS 2x16KB for NPROD=1).
// NPROD=2 (KSTEP=32 only): B = (B0,B1), staged once each, A-frags reused.
// EPI 0: store f16. EPI 1: store fp32*scale. EPI 2: store f16*scale.
// Callers pass tile coords (n0,c0) — XCD-affine swizzle done by caller.
// =====================================================================
template<int NPROD, int EPI, int KSTEP, int LDA, int LDB, int LDC, int KTOT>
__device__ __forceinline__ void gemm_core(
    const f16* __restrict__ A, const f16* __restrict__ B0,
    const f16* __restrict__ B1,
    float* __restrict__ Cf, f16* __restrict__ Ch, float scale,
    int n0, int c0)
{
    constexpr int NKK = KSTEP / 32;
    __shared__ f16 sA[128 * KSTEP];
    __shared__ f16 sB0[128 * KSTEP];
    __shared__ f16 sB1[(NPROD == 2) ? 128 * KSTEP : 64];

    const int t = threadIdx.x;
    const int w = t >> 6;              // wave 0..3
    const int l = t & 63;              // lane
    const int wr = w >> 1, wc = w & 1; // wave's 64x64 quadrant
    const int fr = l & 15;             // fragment row/col
    const int fq = l >> 4;             // fragment quad 0..3

    f32x4 acc[4][4] = {};

    for (int k0 = 0; k0 < KTOT; k0 += KSTEP) {
        // ---- stage: global -> LDS, 16B/lane ----
        if constexpr (KSTEP == 32) {
            const int lrow = l >> 2;          // sub-row 0..15
            const int lch  = l & 3;           // 16B chunk 0..3
#pragma unroll
            for (int i = 0; i < 2; ++i) {
                const int rb  = w * 2 + i;    // row-block (16 rows)
                const int row = rb * 16 + lrow;
                const f16* ga = A + (size_t)(n0 + row) * LDA + k0 + lch * 8;
                __builtin_amdgcn_global_load_lds((g_void*)ga, (lds_void*)(sA + rb * 512), 16, 0, 0);
                const f16* gb0 = B0 + (size_t)(c0 + row) * LDB + k0 + lch * 8;
                __builtin_amdgcn_global_load_lds((g_void*)gb0, (lds_void*)(sB0 + rb * 512), 16, 0, 0);
                if constexpr (NPROD == 2) {
                    const f16* gb1 = B1 + (size_t)(c0 + row) * LDB + k0 + lch * 8;
                    __builtin_amdgcn_global_load_lds((g_void*)gb1, (lds_void*)(sB1 + rb * 512), 16, 0, 0);
                }
            }
        } else {
            const int lrow = l >> 3;          // sub-row 0..7
            const int lch  = l & 7;           // 16B chunk 0..7
#pragma unroll
            for (int i = 0; i < 4; ++i) {
                const int rb  = w * 4 + i;    // row-block (8 rows)
                const int row = rb * 8 + lrow;
                const f16* ga = A + (size_t)(n0 + row) * LDA + k0 + lch * 8;
                __builtin_amdgcn_global_load_lds((g_void*)ga, (lds_void*)(sA + rb * 512), 16, 0, 0);
                const f16* gb0 = B0 + (size_t)(c0 + row) * LDB + k0 + lch * 8;
                __builtin_amdgcn_global_load_lds((g_void*)gb0, (lds_void*)(sB0 + rb * 512), 16, 0, 0);
            }
        }
        __syncthreads();

        // ---- fragments ----
        f16x8 a[4][NKK], b0[4][NKK], b1[4][NKK];
#pragma unroll
        for (int i = 0; i < 4; ++i)
#pragma unroll
            for (int kk = 0; kk < NKK; ++kk) {
                a[i][kk]  = *(const f16x8*)(sA  + (wr * 64 + i * 16 + fr) * KSTEP + kk * 32 + fq * 8);
                b0[i][kk] = *(const f16x8*)(sB0 + (wc * 64 + i * 16 + fr) * KSTEP + kk * 32 + fq * 8);
                if constexpr (NPROD == 2)
                    b1[i][kk] = *(const f16x8*)(sB1 + (wc * 64 + i * 16 + fr) * KSTEP + kk * 32 + fq * 8);
            }

        // ---- MFMA ----
#pragma unroll
        for (int kk = 0; kk < NKK; ++kk)
#pragma unroll
            for (int i = 0; i < 4; ++i)
#pragma unroll
                for (int j = 0; j < 4; ++j) {
                    acc[i][j] = __builtin_amdgcn_mfma_f32_16x16x32_f16(a[i][kk], b0[j][kk], acc[i][j], 0, 0, 0);
                    if constexpr (NPROD == 2)
                        acc[i][j] = __builtin_amdgcn_mfma_f32_16x16x32_f16(a[i][kk], b1[j][kk], acc[i][j], 0, 0, 0);
                }
        __syncthreads();
    }

    // ---- epilogue: C/D layout col=lane&15, row=quad*4+reg ----
#pragma unroll
    for (int i = 0; i < 4; ++i)
#pragma unroll
        for (int j = 0; j < 4; ++j)
#pragma unroll
            for (int r = 0; r < 4; ++r) {
                const int row = n0 + wr * 64 + i * 16 + fq * 4 + r;
                const int col = c0 + wc * 64 + j * 16 + fr;
                const size_t idx = (size_t)row * LDC + col;
                if constexpr (EPI == 1)
                    Cf[idx] = acc[i][j][r] * scale;
                else if constexpr (EPI == 2)
                    Ch[idx] = (f16)(acc[i][j][r] * scale);
                else
                    Ch[idx] = (f16)acc[i][j][r];
            }
}

// GEMM1: Yh[z] = f16( x[b] @ (Wh+Wl)[h] ), z=b*4+h. xcd = b.
__global__ __launch_bounds__(256) void k_g1(
    const f16* __restrict__ xfh, const f16* __restrict__ wTh,
    const f16* __restrict__ wTl, f16* __restrict__ Yh)
{
    const int i = blockIdx.x;
    const int b = i & 7;
    const int li = i >> 3;
    const int h = li >> 5;
    const int n0 = ((li >> 2) & 7) * 128;
    const int e0 = (li & 3) * 128;
    const int z = b * 4 + h;
    gemm_core<2, 0, 32, D_, D_, D_, D_>(
        xfh + (size_t)b * ND,
        wTh + (size_t)h * DD, wTl + (size_t)h * DD,
        nullptr, Yh + (size_t)z * ND, 1.0f, n0, e0);
}

// GEMM2 (full batch): S[z] = f16( Yh[z] @ xh[b]^T * scale ). xcd = b,
// h-major inside so per-XCD set = Yh[z] (1MB) + xh[b] (1MB) <= L2.
__global__ __launch_bounds__(256) void k_g2(
    const f16* __restrict__ Yh, const f16* __restrict__ xfh,
    f16* __restrict__ S)
{
    const int i = blockIdx.x;
    const int b = i & 7;
    const int li = i >> 3;           // 0..255
    const int h = li >> 6;
    const int n0 = ((li >> 3) & 7) * 128;
    const int m0 = (li & 7) * 128;
    const int z = b * 4 + h;
    gemm_core<1, 2, 64, D_, D_, N_, D_>(
        Yh + (size_t)z * ND,
        xfh + (size_t)b * ND, nullptr,
        nullptr, S + (size_t)z * NN, 0.044194173824159216f, n0, m0);
}

// GEMM4 split-K by head: part[z] = f16( P[z] @ xT[b]^T ), z=b*4+h. xcd = b.
__global__ __launch_bounds__(256) void k_g4(
    const f16* __restrict__ P, const f16* __restrict__ xT,
    f16* __restrict__ part)
{
    const int i = blockIdx.x;
    const int b = i & 7;
    const int li = i >> 3;
    const int h = li >> 5;
    const int n0 = ((li >> 2) & 7) * 128;
    const int d0 = (li & 3) * 128;
    const int z = b * 4 + h;
    gemm_core<1, 0, 64, N_, N_, D_, N_>(
        P + (size_t)z * NN,
        xT + (size_t)b * ND, nullptr,
        nullptr, part + (size_t)z * ND, 1.0f, n0, d0);
}

// Reduce: out[b] = 0.25 * sum_h part[b*4+h]   (f16 partials, 8 elems/thread)
__global__ __launch_bounds__(256) void k_reduce(
    const f16* __restrict__ part, float* __restrict__ out)
{
    const int i = blockIdx.x * 256 + threadIdx.x;   // 8-elem group index
    const int b = i / (ND / 8);
    const int r = i - b * (ND / 8);
    const f16x8* p = (const f16x8*)part;
    f16x8 a0 = p[(size_t)(b * 4 + 0) * (ND / 8) + r];
    f16x8 a1 = p[(size_t)(b * 4 + 1) * (ND / 8) + r];
    f16x8 a2 = p[(size_t)(b * 4 + 2) * (ND / 8) + r];
    f16x8 a3 = p[(size_t)(b * 4 + 3) * (ND / 8) + r];
    float4 o0, o1;
    float* o = (float*)&o0;
#pragma unroll
    for (int k = 0; k < 4; ++k)
        o[k] = 0.25f * ((float)a0[k] + (float)a1[k] + (float)a2[k] + (float)a3[k]);
    o = (float*)&o1;
#pragma unroll
    for (int k = 0; k < 4; ++k)
        o[k] = 0.25f * ((float)a0[k+4] + (float)a1[k+4] + (float)a2[k+4] + (float)a3[k+4]);
    ((float4*)out)[(size_t)i * 2]     = o0;
    ((float4*)out)[(size_t)i * 2 + 1] = o1;
}

// Decompose x -> fp16 hi and transposed hi [b][d][n]
__global__ __launch_bounds__(256) void decomp_x(
    const float* __restrict__ x, f16* __restrict__ xfh, f16* __restrict__ xT)
{
    __shared__ f16 tile[64][65];
    const int b = blockIdx.z, n0 = blockIdx.y * 64, d0 = blockIdx.x * 64;
    const float* xb = x + (size_t)b * ND;
    const int t = threadIdx.x;
#pragma unroll
    for (int p = 0; p < 16; ++p) {
        const int idx = t + p * 256;
        const int r = idx >> 6, c = idx & 63;
        const float v = xb[(size_t)(n0 + r) * D_ + d0 + c];
        const f16 h = (f16)v;
        xfh[(size_t)b * ND + (size_t)(n0 + r) * D_ + d0 + c] = h;
        tile[r][c] = h;
    }
    __syncthreads();
#pragma unroll
    for (int p = 0; p < 16; ++p) {
        const int idx = t + p * 256;
        const int r = idx >> 6, c = idx & 63;   // r = local d, c = local n
        xT[(size_t)b * ND + (size_t)(d0 + r) * N_ + n0 + c] = tile[c][r];
    }
}

// Decompose + transpose W: W[h][d][e] -> wTh/wTl fp16 [h][e][d]
__global__ __launch_bounds__(256) void decomp_w(
    const float* __restrict__ W, f16* __restrict__ wTh, f16* __restrict__ wTl)
{
    __shared__ float tw[64][65];
    const int h = blockIdx.z, d0 = blockIdx.y * 64, e0 = blockIdx.x * 64;
    const float* Wh = W + (size_t)h * DD;
    const int t = threadIdx.x;
#pragma unroll
    for (int p = 0; p < 16; ++p) {
        const int idx = t + p * 256;
        const int r = idx >> 6, c = idx & 63;
        tw[r][c] = Wh[(size_t)(d0 + r) * D_ + e0 + c];
    }
    __syncthreads();
#pragma unroll
    for (int p = 0; p < 16; ++p) {
        const int idx = t + p * 256;
        const int r = idx >> 6, c = idx & 63;   // r = local e, c = local d
        const float v = tw[c][r];
        const f16 hh = (f16)v;
        const size_t o = (size_t)h * DD + (size_t)(e0 + r) * D_ + d0 + c;
        wTh[o] = hh;
        wTl[o] = (f16)(v - (float)hh);
    }
}

// Rowwise softmax f16 S -> f16 P. One block per row of 1024.
__global__ __launch_bounds__(256) void softmax_rows_f16(
    const f16* __restrict__ S, f16* __restrict__ P)
{
    const size_t row = blockIdx.x;
    const f16x4* p = (const f16x4*)(S + row * (size_t)N_);
    const int t = threadIdx.x;

    f16x4 vh = p[t];
    float4 v;
    v.x = (float)vh[0]; v.y = (float)vh[1];
    v.z = (float)vh[2]; v.w = (float)vh[3];
    float m = fmaxf(fmaxf(v.x, v.y), fmaxf(v.z, v.w));
#pragma unroll
    for (int o = 32; o > 0; o >>= 1) m = fmaxf(m, __shfl_xor(m, o));

    __shared__ float wred[4];
    const int wave = t >> 6, lane = t & 63;
    if (lane == 0) wred[wave] = m;
    __syncthreads();
    m = fmaxf(fmaxf(wred[0], wred[1]), fmaxf(wred[2], wred[3]));

    v.x = __expf(v.x - m);
    v.y = __expf(v.y - m);
    v.z = __expf(v.z - m);
    v.w = __expf(v.w - m);
    float s = v.x + v.y + v.z + v.w;
#pragma unroll
    for (int o = 32; o > 0; o >>= 1) s += __shfl_xor(s, o);
    __syncthreads();
    if (lane == 0) wred[wave] = s;
    __syncthreads();
    s = wred[0] + wred[1] + wred[2] + wred[3];

    const float inv = 1.0f / s;
    f16x4 o4;
    o4[0] = (f16)(v.x * inv);
    o4[1] = (f16)(v.y * inv);
    o4[2] = (f16)(v.z * inv);
    o4[3] = (f16)(v.w * inv);
    *(f16x4*)(P + row * (size_t)N_ + t * 4) = o4;
}

extern "C" void kernel_launch(void* const* d_in, const int* in_sizes, int n_in,
                              void* d_out, int out_size, void* d_ws, size_t ws_size,
                              hipStream_t stream) {
    const float* x = (const float*)d_in[0];   // [8,1024,512]
    const float* W = (const float*)d_in[1];   // [4,512,512]
    float* out = (float*)d_out;               // [8,1024,512]

    // workspace layout, 180 MiB (footprint proven in R2-R5)
    char* ws = (char*)d_ws;
    const size_t MB = 1024 * 1024;
    f16*   xfh = (f16*)(ws + 0 * MB);     // 8 MiB
    f16*   xT  = (f16*)(ws + 8 * MB);     // 8 MiB
    f16*   wTh = (f16*)(ws + 16 * MB);    // 2 MiB
    f16*   wTl = (f16*)(ws + 18 * MB);    // 2 MiB
    f16*   Yh  = (f16*)(ws + 20 * MB);    // 32 MiB (full batch, 32 z)
    f16*   S   = (f16*)(ws + 52 * MB);    // 64 MiB (full batch, f16)
    f16*   P   = (f16*)(ws + 116 * MB);   // 64 MiB (full batch, f16)
    f16*   part = S;                      // g4 partials (32 MiB) reuse S

    decomp_x<<<dim3(D_ / 64, N_ / 64, B_), 256, 0, stream>>>(x, xfh, xT);
    decomp_w<<<dim3(D_ / 64, D_ / 64, H_), 256, 0, stream>>>(W, wTh, wTl);

    k_g1<<<dim3(1024), 256, 0, stream>>>(xfh, wTh, wTl, Yh);
    k_g2<<<dim3(2048), 256, 0, stream>>>(Yh, xfh, S);
    softmax_rows_f16<<<dim3(B_ * H_ * N_), 256, 0, stream>>>(S, P);
    k_g4<<<dim3(1024), 256, 0, stream>>>(P, xT, part);
    k_reduce<<<dim3((B_ * ND / 8) / 256), 256, 0, stream>>>(part, out);
}

// Round 7
// 242.999 us; speedup vs baseline: 1.7491x; 1.0497x over previous
//
#include <hip/hip_runtime.h>
#include <math.h>

#define B_ 8
#define N_ 1024
#define D_ 512
#define H_ 4
#define ND (N_ * D_)      // 524288
#define DD (D_ * D_)      // 262144
#define NN (N_ * N_)      // 1048576

typedef _Float16 f16;
typedef f16 f16x8 __attribute__((ext_vector_type(8)));
typedef f16 f16x4 __attribute__((ext_vector_type(4)));
typedef float f32x4 __attribute__((ext_vector_type(4)));

typedef __attribute__((address_space(3))) void lds_void;
typedef __attribute__((address_space(1))) void g_void;

// =====================================================================
// m97-structure GEMM core, 128x128 C-tile, BK=32, 16x16x32 f16 MFMA,
// global_load_lds width-16 staging, 2-barrier K-loop.  (KSTEP=32 proven
// optimal in R5/R6 A-B: KSTEP=64 regressed via VGPR/occupancy.)
// NPROD=2: B = (B0,B1), each staged once/iter, A-frags reused.
// EPI 0: store f16. EPI 1: store fp32*scale. EPI 2: store f16*scale.
// Callers pass tile coords (n0,c0) — XCD-affine swizzle done by caller.
// =====================================================================
template<int NPROD, int EPI, int LDA, int LDB, int LDC, int KTOT>
__device__ __forceinline__ void gemm_core(
    const f16* __restrict__ A, const f16* __restrict__ B0,
    const f16* __restrict__ B1,
    float* __restrict__ Cf, f16* __restrict__ Ch, float scale,
    int n0, int c0)
{
    __shared__ f16 sA[128 * 32];
    __shared__ f16 sB0[128 * 32];
    __shared__ f16 sB1[(NPROD == 2) ? 128 * 32 : 64];

    const int t = threadIdx.x;
    const int w = t >> 6;              // wave 0..3
    const int l = t & 63;              // lane
    const int lrow = l >> 2;           // staging sub-row 0..15
    const int lch  = l & 3;            // staging 16B chunk 0..3
    const int wr = w >> 1, wc = w & 1; // wave's 64x64 quadrant
    const int fr = l & 15;             // fragment row/col
    const int fq = l >> 4;             // fragment quad 0..3

    f32x4 acc[4][4] = {};

    for (int k0 = 0; k0 < KTOT; k0 += 32) {
        // ---- stage: global -> LDS, 16B/lane, each buffer once ----
#pragma unroll
        for (int i = 0; i < 2; ++i) {
            const int rb  = w * 2 + i;            // row-block 0..7
            const int row = rb * 16 + lrow;       // 0..127
            const f16* ga = A + (size_t)(n0 + row) * LDA + k0 + lch * 8;
            __builtin_amdgcn_global_load_lds((g_void*)ga, (lds_void*)(sA + rb * 512), 16, 0, 0);
            const f16* gb0 = B0 + (size_t)(c0 + row) * LDB + k0 + lch * 8;
            __builtin_amdgcn_global_load_lds((g_void*)gb0, (lds_void*)(sB0 + rb * 512), 16, 0, 0);
            if constexpr (NPROD == 2) {
                const f16* gb1 = B1 + (size_t)(c0 + row) * LDB + k0 + lch * 8;
                __builtin_amdgcn_global_load_lds((g_void*)gb1, (lds_void*)(sB1 + rb * 512), 16, 0, 0);
            }
        }
        __syncthreads();

        // ---- fragments (A reused across both products) ----
        f16x8 a[4], b0[4], b1[4];
#pragma unroll
        for (int i = 0; i < 4; ++i) {
            a[i]  = *(const f16x8*)(sA  + (wr * 64 + i * 16 + fr) * 32 + fq * 8);
            b0[i] = *(const f16x8*)(sB0 + (wc * 64 + i * 16 + fr) * 32 + fq * 8);
            if constexpr (NPROD == 2)
                b1[i] = *(const f16x8*)(sB1 + (wc * 64 + i * 16 + fr) * 32 + fq * 8);
        }

        // ---- MFMA ----
#pragma unroll
        for (int i = 0; i < 4; ++i)
#pragma unroll
            for (int j = 0; j < 4; ++j) {
                acc[i][j] = __builtin_amdgcn_mfma_f32_16x16x32_f16(a[i], b0[j], acc[i][j], 0, 0, 0);
                if constexpr (NPROD == 2)
                    acc[i][j] = __builtin_amdgcn_mfma_f32_16x16x32_f16(a[i], b1[j], acc[i][j], 0, 0, 0);
            }
        __syncthreads();
    }

    // ---- epilogue: C/D layout col=lane&15, row=quad*4+reg ----
#pragma unroll
    for (int i = 0; i < 4; ++i)
#pragma unroll
        for (int j = 0; j < 4; ++j)
#pragma unroll
            for (int r = 0; r < 4; ++r) {
                const int row = n0 + wr * 64 + i * 16 + fq * 4 + r;
                const int col = c0 + wc * 64 + j * 16 + fr;
                const size_t idx = (size_t)row * LDC + col;
                if constexpr (EPI == 1)
                    Cf[idx] = acc[i][j][r] * scale;
                else if constexpr (EPI == 2)
                    Ch[idx] = (f16)(acc[i][j][r] * scale);
                else
                    Ch[idx] = (f16)acc[i][j][r];
            }
}

// GEMM1: Yh[z] = f16( x[b] @ (Wh+Wl)[h] ), z=b*4+h. xcd = b.
__global__ __launch_bounds__(256) void k_g1(
    const f16* __restrict__ xfh, const f16* __restrict__ wTh,
    const f16* __restrict__ wTl, f16* __restrict__ Yh)
{
    const int i = blockIdx.x;
    const int b = i & 7;
    const int li = i >> 3;
    const int h = li >> 5;
    const int n0 = ((li >> 2) & 7) * 128;
    const int e0 = (li & 3) * 128;
    const int z = b * 4 + h;
    gemm_core<2, 0, D_, D_, D_, D_>(
        xfh + (size_t)b * ND,
        wTh + (size_t)h * DD, wTl + (size_t)h * DD,
        nullptr, Yh + (size_t)z * ND, 1.0f, n0, e0);
}

// GEMM2 (full batch): S[z] = f16( Yh[z] @ xh[b]^T * scale ). xcd = b,
// per-XCD set = Yh[b] (4MB worst) + xh[b] (1MB); h-major inside.
__global__ __launch_bounds__(256) void k_g2(
    const f16* __restrict__ Yh, const f16* __restrict__ xfh,
    f16* __restrict__ S)
{
    const int i = blockIdx.x;
    const int b = i & 7;
    const int li = i >> 3;           // 0..255
    const int h = li >> 6;
    const int n0 = ((li >> 3) & 7) * 128;
    const int m0 = (li & 7) * 128;
    const int z = b * 4 + h;
    gemm_core<1, 2, D_, D_, N_, D_>(
        Yh + (size_t)z * ND,
        xfh + (size_t)b * ND, nullptr,
        nullptr, S + (size_t)z * NN, 0.044194173824159216f, n0, m0);
}

// GEMM4 split-K by head: part[z] = f16( P[z] @ xT[b]^T ), z=b*4+h. xcd = b.
__global__ __launch_bounds__(256) void k_g4(
    const f16* __restrict__ P, const f16* __restrict__ xT,
    f16* __restrict__ part)
{
    const int i = blockIdx.x;
    const int b = i & 7;
    const int li = i >> 3;
    const int h = li >> 5;
    const int n0 = ((li >> 2) & 7) * 128;
    const int d0 = (li & 3) * 128;
    const int z = b * 4 + h;
    gemm_core<1, 0, N_, N_, D_, N_>(
        P + (size_t)z * NN,
        xT + (size_t)b * ND, nullptr,
        nullptr, part + (size_t)z * ND, 1.0f, n0, d0);
}

// Reduce: out[b] = 0.25 * sum_h part[b*4+h]   (f16 partials, 8 elems/thread)
__global__ __launch_bounds__(256) void k_reduce(
    const f16* __restrict__ part, float* __restrict__ out)
{
    const int i = blockIdx.x * 256 + threadIdx.x;   // 8-elem group index
    const int b = i / (ND / 8);
    const int r = i - b * (ND / 8);
    const f16x8* p = (const f16x8*)part;
    f16x8 a0 = p[(size_t)(b * 4 + 0) * (ND / 8) + r];
    f16x8 a1 = p[(size_t)(b * 4 + 1) * (ND / 8) + r];
    f16x8 a2 = p[(size_t)(b * 4 + 2) * (ND / 8) + r];
    f16x8 a3 = p[(size_t)(b * 4 + 3) * (ND / 8) + r];
    float4 o0, o1;
    float* o = (float*)&o0;
#pragma unroll
    for (int k = 0; k < 4; ++k)
        o[k] = 0.25f * ((float)a0[k] + (float)a1[k] + (float)a2[k] + (float)a3[k]);
    o = (float*)&o1;
#pragma unroll
    for (int k = 0; k < 4; ++k)
        o[k] = 0.25f * ((float)a0[k+4] + (float)a1[k+4] + (float)a2[k+4] + (float)a3[k+4]);
    ((float4*)out)[(size_t)i * 2]     = o0;
    ((float4*)out)[(size_t)i * 2 + 1] = o1;
}

// Decompose x -> fp16 hi and transposed hi [b][d][n]
__global__ __launch_bounds__(256) void decomp_x(
    const float* __restrict__ x, f16* __restrict__ xfh, f16* __restrict__ xT)
{
    __shared__ f16 tile[64][65];
    const int b = blockIdx.z, n0 = blockIdx.y * 64, d0 = blockIdx.x * 64;
    const float* xb = x + (size_t)b * ND;
    const int t = threadIdx.x;
#pragma unroll
    for (int p = 0; p < 16; ++p) {
        const int idx = t + p * 256;
        const int r = idx >> 6, c = idx & 63;
        const float v = xb[(size_t)(n0 + r) * D_ + d0 + c];
        const f16 h = (f16)v;
        xfh[(size_t)b * ND + (size_t)(n0 + r) * D_ + d0 + c] = h;
        tile[r][c] = h;
    }
    __syncthreads();
#pragma unroll
    for (int p = 0; p < 16; ++p) {
        const int idx = t + p * 256;
        const int r = idx >> 6, c = idx & 63;   // r = local d, c = local n
        xT[(size_t)b * ND + (size_t)(d0 + r) * N_ + n0 + c] = tile[c][r];
    }
}

// Decompose + transpose W: W[h][d][e] -> wTh/wTl fp16 [h][e][d]
__global__ __launch_bounds__(256) void decomp_w(
    const float* __restrict__ W, f16* __restrict__ wTh, f16* __restrict__ wTl)
{
    __shared__ float tw[64][65];
    const int h = blockIdx.z, d0 = blockIdx.y * 64, e0 = blockIdx.x * 64;
    const float* Wh = W + (size_t)h * DD;
    const int t = threadIdx.x;
#pragma unroll
    for (int p = 0; p < 16; ++p) {
        const int idx = t + p * 256;
        const int r = idx >> 6, c = idx & 63;
        tw[r][c] = Wh[(size_t)(d0 + r) * D_ + e0 + c];
    }
    __syncthreads();
#pragma unroll
    for (int p = 0; p < 16; ++p) {
        const int idx = t + p * 256;
        const int r = idx >> 6, c = idx & 63;   // r = local e, c = local d
        const float v = tw[c][r];
        const f16 hh = (f16)v;
        const size_t o = (size_t)h * DD + (size_t)(e0 + r) * D_ + d0 + c;
        wTh[o] = hh;
        wTl[o] = (f16)(v - (float)hh);
    }
}

// Barrier-free softmax: one WAVE per row of 1024 (16 f16/lane, 2x b128).
// Pure shuffle reductions — no LDS, no __syncthreads. 4 rows per block.
__global__ __launch_bounds__(256) void softmax_wave(
    const f16* __restrict__ S, f16* __restrict__ P)
{
    const int wave = threadIdx.x >> 6;
    const int l = threadIdx.x & 63;
    const size_t row = (size_t)blockIdx.x * 4 + wave;

    const f16x8* p = (const f16x8*)(S + row * N_);
    f16x8 v0 = p[l * 2], v1 = p[l * 2 + 1];

    float f[16];
#pragma unroll
    for (int k = 0; k < 8; ++k) { f[k] = (float)v0[k]; f[k + 8] = (float)v1[k]; }

    float m = f[0];
#pragma unroll
    for (int k = 1; k < 16; ++k) m = fmaxf(m, f[k]);
#pragma unroll
    for (int o = 32; o > 0; o >>= 1) m = fmaxf(m, __shfl_xor(m, o));

    float s = 0.f;
#pragma unroll
    for (int k = 0; k < 16; ++k) { f[k] = __expf(f[k] - m); s += f[k]; }
#pragma unroll
    for (int o = 32; o > 0; o >>= 1) s += __shfl_xor(s, o);

    const float inv = 1.0f / s;
    f16x8 o0, o1;
#pragma unroll
    for (int k = 0; k < 8; ++k) {
        o0[k] = (f16)(f[k] * inv);
        o1[k] = (f16)(f[k + 8] * inv);
    }
    f16x8* q = (f16x8*)(P + row * N_);
    q[l * 2] = o0;
    q[l * 2 + 1] = o1;
}

extern "C" void kernel_launch(void* const* d_in, const int* in_sizes, int n_in,
                              void* d_out, int out_size, void* d_ws, size_t ws_size,
                              hipStream_t stream) {
    const float* x = (const float*)d_in[0];   // [8,1024,512]
    const float* W = (const float*)d_in[1];   // [4,512,512]
    float* out = (float*)d_out;               // [8,1024,512]

    // workspace layout, 180 MiB (footprint proven in R2-R6)
    char* ws = (char*)d_ws;
    const size_t MB = 1024 * 1024;
    f16*   xfh = (f16*)(ws + 0 * MB);     // 8 MiB
    f16*   xT  = (f16*)(ws + 8 * MB);     // 8 MiB
    f16*   wTh = (f16*)(ws + 16 * MB);    // 2 MiB
    f16*   wTl = (f16*)(ws + 18 * MB);    // 2 MiB
    f16*   Yh  = (f16*)(ws + 20 * MB);    // 32 MiB (full batch, 32 z)
    f16*   S   = (f16*)(ws + 52 * MB);    // 64 MiB (full batch, f16)
    f16*   P   = (f16*)(ws + 116 * MB);   // 64 MiB (full batch, f16)
    f16*   part = S;                      // g4 partials (32 MiB) reuse S

    decomp_x<<<dim3(D_ / 64, N_ / 64, B_), 256, 0, stream>>>(x, xfh, xT);
    decomp_w<<<dim3(D_ / 64, D_ / 64, H_), 256, 0, stream>>>(W, wTh, wTl);

    k_g1<<<dim3(1024), 256, 0, stream>>>(xfh, wTh, wTl, Yh);
    k_g2<<<dim3(2048), 256, 0, stream>>>(Yh, xfh, S);
    softmax_wave<<<dim3(B_ * H_ * N_ / 4), 256, 0, stream>>>(S, P);
    k_g4<<<dim3(1024), 256, 0, stream>>>(P, xT, part);
    k_reduce<<<dim3((B_ * ND / 8) / 256), 256, 0, stream>>>(part, out);
}

// Round 8
// 216.293 us; speedup vs baseline: 1.9650x; 1.1235x over previous
//
#include <hip/hip_runtime.h>
#include <math.h>

#define B_ 8
#define N_ 1024
#define D_ 512
#define H_ 4
#define ND (N_ * D_)      // 524288
#define DD (D_ * D_)      // 262144
#define NN (N_ * N_)      // 1048576

typedef _Float16 f16;
typedef f16 f16x8 __attribute__((ext_vector_type(8)));
typedef f16 f16x4 __attribute__((ext_vector_type(4)));
typedef float f32x4 __attribute__((ext_vector_type(4)));

typedef __attribute__((address_space(3))) void lds_void;
typedef __attribute__((address_space(1))) void g_void;

// =====================================================================
// Paired-tile m97-structure GEMM: each block computes TWO stacked
// 128x128 C-tiles (rows n0..n0+256) sharing the staged B tile.
// BK=32, 16x16x32 f16 MFMA, global_load_lds width-16, 2-barrier K-loop.
// Per iter: stage 3 tiles -> 32 MFMA/wave (NPROD=1), or 4 tiles -> 64
// MFMA/wave (NPROD=2, B=(B0,B1) with A-frags reused: C = A*(B0+B1)^T).
// EPI 0: store f16. EPI 2: store f16*scale.
// acc = 128 VGPR -> __launch_bounds__(256,2).
// =====================================================================
template<int NPROD, int EPI, int LDA, int LDB, int LDC, int KTOT>
__device__ __forceinline__ void pair_core(
    const f16* __restrict__ A, const f16* __restrict__ B0,
    const f16* __restrict__ B1, f16* __restrict__ Ch, float scale,
    int n0, int c0)
{
    __shared__ f16 sA[256 * 32];                       // 16 KB
    __shared__ f16 sB0[128 * 32];                      //  8 KB
    __shared__ f16 sB1[(NPROD == 2) ? 128 * 32 : 64];  //  8 KB if used

    const int t = threadIdx.x;
    const int w = t >> 6;              // wave 0..3
    const int l = t & 63;              // lane
    const int lrow = l >> 2;           // staging sub-row 0..15
    const int lch  = l & 3;            // staging 16B chunk 0..3
    const int wr = w >> 1, wc = w & 1; // 64x64 quadrant within a 128-tile
    const int fr = l & 15;             // fragment row/col
    const int fq = l >> 4;             // fragment quad 0..3

    f32x4 acc0[4][4] = {};
    f32x4 acc1[4][4] = {};

    for (int k0 = 0; k0 < KTOT; k0 += 32) {
        // ---- stage A (256 rows): 4 row-blocks per wave ----
#pragma unroll
        for (int i = 0; i < 4; ++i) {
            const int rb  = w * 4 + i;            // 0..15
            const int row = rb * 16 + lrow;       // 0..255
            const f16* ga = A + (size_t)(n0 + row) * LDA + k0 + lch * 8;
            __builtin_amdgcn_global_load_lds((g_void*)ga, (lds_void*)(sA + rb * 512), 16, 0, 0);
        }
        // ---- stage B (128 rows): 2 row-blocks per wave ----
#pragma unroll
        for (int i = 0; i < 2; ++i) {
            const int rb  = w * 2 + i;            // 0..7
            const int row = rb * 16 + lrow;       // 0..127
            const f16* gb0 = B0 + (size_t)(c0 + row) * LDB + k0 + lch * 8;
            __builtin_amdgcn_global_load_lds((g_void*)gb0, (lds_void*)(sB0 + rb * 512), 16, 0, 0);
            if constexpr (NPROD == 2) {
                const f16* gb1 = B1 + (size_t)(c0 + row) * LDB + k0 + lch * 8;
                __builtin_amdgcn_global_load_lds((g_void*)gb1, (lds_void*)(sB1 + rb * 512), 16, 0, 0);
            }
        }
        __syncthreads();

        // ---- fragments (b shared across both A tiles) ----
        f16x8 a0[4], a1[4], b0[4], b1[4];
#pragma unroll
        for (int i = 0; i < 4; ++i) {
            a0[i] = *(const f16x8*)(sA + (wr * 64 + i * 16 + fr) * 32 + fq * 8);
            a1[i] = *(const f16x8*)(sA + (128 * 32) + (wr * 64 + i * 16 + fr) * 32 + fq * 8);
            b0[i] = *(const f16x8*)(sB0 + (wc * 64 + i * 16 + fr) * 32 + fq * 8);
            if constexpr (NPROD == 2)
                b1[i] = *(const f16x8*)(sB1 + (wc * 64 + i * 16 + fr) * 32 + fq * 8);
        }

        // ---- MFMA: 32 (NPROD=1) or 64 (NPROD=2) per wave-iter ----
#pragma unroll
        for (int i = 0; i < 4; ++i)
#pragma unroll
            for (int j = 0; j < 4; ++j) {
                acc0[i][j] = __builtin_amdgcn_mfma_f32_16x16x32_f16(a0[i], b0[j], acc0[i][j], 0, 0, 0);
                acc1[i][j] = __builtin_amdgcn_mfma_f32_16x16x32_f16(a1[i], b0[j], acc1[i][j], 0, 0, 0);
                if constexpr (NPROD == 2) {
                    acc0[i][j] = __builtin_amdgcn_mfma_f32_16x16x32_f16(a0[i], b1[j], acc0[i][j], 0, 0, 0);
                    acc1[i][j] = __builtin_amdgcn_mfma_f32_16x16x32_f16(a1[i], b1[j], acc1[i][j], 0, 0, 0);
                }
            }
        __syncthreads();
    }

    // ---- epilogue: C/D layout col=lane&15, row=quad*4+reg; two tiles ----
#pragma unroll
    for (int i = 0; i < 4; ++i)
#pragma unroll
        for (int j = 0; j < 4; ++j)
#pragma unroll
            for (int r = 0; r < 4; ++r) {
                const int row = n0 + wr * 64 + i * 16 + fq * 4 + r;
                const int col = c0 + wc * 64 + j * 16 + fr;
                const size_t i0 = (size_t)row * LDC + col;
                const size_t i1 = (size_t)(row + 128) * LDC + col;
                if constexpr (EPI == 2) {
                    Ch[i0] = (f16)(acc0[i][j][r] * scale);
                    Ch[i1] = (f16)(acc1[i][j][r] * scale);
                } else {
                    Ch[i0] = (f16)acc0[i][j][r];
                    Ch[i1] = (f16)acc1[i][j][r];
                }
            }
}

// GEMM1: Yh[z] = f16( x[b] @ (Wh+Wl)[h] ), z=b*4+h. xcd = b. 512 blocks.
__global__ __launch_bounds__(256, 2) void k_g1(
    const f16* __restrict__ xfh, const f16* __restrict__ wTh,
    const f16* __restrict__ wTl, f16* __restrict__ Yh)
{
    const int i = blockIdx.x;
    const int b = i & 7;
    const int li = i >> 3;            // 0..63
    const int h = li >> 4;
    const int n0 = ((li >> 2) & 3) * 256;
    const int e0 = (li & 3) * 128;
    const int z = b * 4 + h;
    pair_core<2, 0, D_, D_, D_, D_>(
        xfh + (size_t)b * ND,
        wTh + (size_t)h * DD, wTl + (size_t)h * DD,
        Yh + (size_t)z * ND, 1.0f, n0, e0);
}

// GEMM2: S[z] = f16( Yh[z] @ xh[b]^T * scale ). xcd = b. 1024 blocks.
__global__ __launch_bounds__(256, 2) void k_g2(
    const f16* __restrict__ Yh, const f16* __restrict__ xfh,
    f16* __restrict__ S)
{
    const int i = blockIdx.x;
    const int b = i & 7;
    const int li = i >> 3;            // 0..127
    const int h = li >> 5;
    const int n0 = ((li >> 3) & 3) * 256;
    const int m0 = (li & 7) * 128;
    const int z = b * 4 + h;
    pair_core<1, 2, D_, D_, N_, D_>(
        Yh + (size_t)z * ND,
        xfh + (size_t)b * ND, nullptr,
        S + (size_t)z * NN, 0.044194173824159216f, n0, m0);
}

// GEMM4 split-K by head: part[z] = f16( P[z] @ xT[b]^T ). xcd = b. 512 blocks.
__global__ __launch_bounds__(256, 2) void k_g4(
    const f16* __restrict__ P, const f16* __restrict__ xT,
    f16* __restrict__ part)
{
    const int i = blockIdx.x;
    const int b = i & 7;
    const int li = i >> 3;            // 0..63
    const int h = li >> 4;
    const int n0 = ((li >> 2) & 3) * 256;
    const int d0 = (li & 3) * 128;
    const int z = b * 4 + h;
    pair_core<1, 0, N_, N_, D_, N_>(
        P + (size_t)z * NN,
        xT + (size_t)b * ND, nullptr,
        part + (size_t)z * ND, 1.0f, n0, d0);
}

// Reduce: out[b] = 0.25 * sum_h part[b*4+h]   (f16 partials, 8 elems/thread)
__global__ __launch_bounds__(256) void k_reduce(
    const f16* __restrict__ part, float* __restrict__ out)
{
    const int i = blockIdx.x * 256 + threadIdx.x;   // 8-elem group index
    const int b = i / (ND / 8);
    const int r = i - b * (ND / 8);
    const f16x8* p = (const f16x8*)part;
    f16x8 a0 = p[(size_t)(b * 4 + 0) * (ND / 8) + r];
    f16x8 a1 = p[(size_t)(b * 4 + 1) * (ND / 8) + r];
    f16x8 a2 = p[(size_t)(b * 4 + 2) * (ND / 8) + r];
    f16x8 a3 = p[(size_t)(b * 4 + 3) * (ND / 8) + r];
    float4 o0, o1;
    float* o = (float*)&o0;
#pragma unroll
    for (int k = 0; k < 4; ++k)
        o[k] = 0.25f * ((float)a0[k] + (float)a1[k] + (float)a2[k] + (float)a3[k]);
    o = (float*)&o1;
#pragma unroll
    for (int k = 0; k < 4; ++k)
        o[k] = 0.25f * ((float)a0[k+4] + (float)a1[k+4] + (float)a2[k+4] + (float)a3[k+4]);
    ((float4*)out)[(size_t)i * 2]     = o0;
    ((float4*)out)[(size_t)i * 2 + 1] = o1;
}

// Merged decomp: z<8 -> x-batch z (f16 hi + transposed hi); z>=8 -> W head
// z-8 (hi/lo + transpose). Grid (8,16,12); W part uses y<8 only.
__global__ __launch_bounds__(256) void decomp_xw(
    const float* __restrict__ x, const float* __restrict__ W,
    f16* __restrict__ xfh, f16* __restrict__ xT,
    f16* __restrict__ wTh, f16* __restrict__ wTl)
{
    __shared__ f16 tile[64][65];
    __shared__ float tw[64][65];
    const int t = threadIdx.x;
    const int z = blockIdx.z;
    if (z < 8) {
        const int b = z, n0 = blockIdx.y * 64, d0 = blockIdx.x * 64;
        const float* xb = x + (size_t)b * ND;
#pragma unroll
        for (int p = 0; p < 16; ++p) {
            const int idx = t + p * 256;
            const int r = idx >> 6, c = idx & 63;
            const float v = xb[(size_t)(n0 + r) * D_ + d0 + c];
            const f16 h = (f16)v;
            xfh[(size_t)b * ND + (size_t)(n0 + r) * D_ + d0 + c] = h;
            tile[r][c] = h;
        }
        __syncthreads();
#pragma unroll
        for (int p = 0; p < 16; ++p) {
            const int idx = t + p * 256;
            const int r = idx >> 6, c = idx & 63;   // r = local d, c = local n
            xT[(size_t)b * ND + (size_t)(d0 + r) * N_ + n0 + c] = tile[c][r];
        }
    } else {
        if (blockIdx.y >= 8) return;
        const int h = z - 8, d0 = blockIdx.y * 64, e0 = blockIdx.x * 64;
        const float* Wh = W + (size_t)h * DD;
#pragma unroll
        for (int p = 0; p < 16; ++p) {
            const int idx = t + p * 256;
            const int r = idx >> 6, c = idx & 63;
            tw[r][c] = Wh[(size_t)(d0 + r) * D_ + e0 + c];
        }
        __syncthreads();
#pragma unroll
        for (int p = 0; p < 16; ++p) {
            const int idx = t + p * 256;
            const int r = idx >> 6, c = idx & 63;   // r = local e, c = local d
            const float v = tw[c][r];
            const f16 hh = (f16)v;
            const size_t o = (size_t)h * DD + (size_t)(e0 + r) * D_ + d0 + c;
            wTh[o] = hh;
            wTl[o] = (f16)(v - (float)hh);
        }
    }
}

// Barrier-free softmax: one WAVE per row of 1024 (16 f16/lane, 2x b128).
__global__ __launch_bounds__(256) void softmax_wave(
    const f16* __restrict__ S, f16* __restrict__ P)
{
    const int wave = threadIdx.x >> 6;
    const int l = threadIdx.x & 63;
    const size_t row = (size_t)blockIdx.x * 4 + wave;

    const f16x8* p = (const f16x8*)(S + row * N_);
    f16x8 v0 = p[l * 2], v1 = p[l * 2 + 1];

    float f[16];
#pragma unroll
    for (int k = 0; k < 8; ++k) { f[k] = (float)v0[k]; f[k + 8] = (float)v1[k]; }

    float m = f[0];
#pragma unroll
    for (int k = 1; k < 16; ++k) m = fmaxf(m, f[k]);
#pragma unroll
    for (int o = 32; o > 0; o >>= 1) m = fmaxf(m, __shfl_xor(m, o));

    float s = 0.f;
#pragma unroll
    for (int k = 0; k < 16; ++k) { f[k] = __expf(f[k] - m); s += f[k]; }
#pragma unroll
    for (int o = 32; o > 0; o >>= 1) s += __shfl_xor(s, o);

    const float inv = 1.0f / s;
    f16x8 o0, o1;
#pragma unroll
    for (int k = 0; k < 8; ++k) {
        o0[k] = (f16)(f[k] * inv);
        o1[k] = (f16)(f[k + 8] * inv);
    }
    f16x8* q = (f16x8*)(P + row * N_);
    q[l * 2] = o0;
    q[l * 2 + 1] = o1;
}

extern "C" void kernel_launch(void* const* d_in, const int* in_sizes, int n_in,
                              void* d_out, int out_size, void* d_ws, size_t ws_size,
                              hipStream_t stream) {
    const float* x = (const float*)d_in[0];   // [8,1024,512]
    const float* W = (const float*)d_in[1];   // [4,512,512]
    float* out = (float*)d_out;               // [8,1024,512]

    // workspace layout, 180 MiB (footprint proven in R2-R7)
    char* ws = (char*)d_ws;
    const size_t MB = 1024 * 1024;
    f16*   xfh = (f16*)(ws + 0 * MB);     // 8 MiB
    f16*   xT  = (f16*)(ws + 8 * MB);     // 8 MiB
    f16*   wTh = (f16*)(ws + 16 * MB);    // 2 MiB
    f16*   wTl = (f16*)(ws + 18 * MB);    // 2 MiB
    f16*   Yh  = (f16*)(ws + 20 * MB);    // 32 MiB (full batch, 32 z)
    f16*   S   = (f16*)(ws + 52 * MB);    // 64 MiB (full batch, f16)
    f16*   P   = (f16*)(ws + 116 * MB);   // 64 MiB (full batch, f16)
    f16*   part = S;                      // g4 partials (32 MiB) reuse S

    decomp_xw<<<dim3(8, 16, 12), 256, 0, stream>>>(x, W, xfh, xT, wTh, wTl);

    k_g1<<<dim3(512), 256, 0, stream>>>(xfh, wTh, wTl, Yh);
    k_g2<<<dim3(1024), 256, 0, stream>>>(Yh, xfh, S);
    softmax_wave<<<dim3(B_ * H_ * N_ / 4), 256, 0, stream>>>(S, P);
    k_g4<<<dim3(512), 256, 0, stream>>>(P, xT, part);
    k_reduce<<<dim3((B_ * ND / 8) / 256), 256, 0, stream>>>(part, out);
}